// Round 6
// baseline (154.066 us; speedup 1.0000x reference)
//
#include <hip/hip_runtime.h>
#include <hip/hip_bf16.h>
#include <cstdio>

// Problem constants: B=2, S=1024, D=256, H=8, K=32
#define PB 2
#define PS 1024
#define PD 256
#define PK 32
#define PH 8
#define HB (PH*PB)          // 16
#define BS (PB*PS)          // 2048
#define EPS 1e-9f

typedef __attribute__((ext_vector_type(8))) short bf16x8;
typedef __attribute__((ext_vector_type(4))) float f32x4;

__device__ inline unsigned short f2bf(float f) {
    __hip_bfloat16 h = __float2bfloat16(f);
    return *reinterpret_cast<unsigned short*>(&h);
}
__device__ inline float bf2f(unsigned short u) {
    return __bfloat162float(*reinterpret_cast<__hip_bfloat16*>(&u));
}

// ---------------- kernel 1: fused prep (xb, WqT, WkT, WvT, WoT) --------------
// flat grid 784: [0,512) xb; [512,528) qk-transpose; [528,656) WvT; [656,784) WoT
__global__ __launch_bounds__(256) void k_prep(
    const float* __restrict__ x, const float* __restrict__ Wqs,
    const float* __restrict__ Wks, const float* __restrict__ Wvs,
    const float* __restrict__ Wo,
    unsigned short* __restrict__ xb, unsigned short* __restrict__ WqT,
    unsigned short* __restrict__ WkT, unsigned short* __restrict__ WvT,
    unsigned short* __restrict__ WoT)
{
    __shared__ float smem[8448];
    int bid = blockIdx.x, tid = threadIdx.x;
    if (bid < 512) {                       // xb: f32 -> bf16
        int i = bid*256 + tid;
        float4 v = ((const float4*)x)[i];
        ushort4 o = {f2bf(v.x), f2bf(v.y), f2bf(v.z), f2bf(v.w)};
        ((ushort4*)xb)[i] = o;
        return;
    }
    if (bid < 528) {                       // Wq/Wk [d 256][kk 32] -> [kk][d]
        int r2 = bid - 512;
        int h = r2 >> 1, isK = r2 & 1;
        const float* S = (isK ? Wks : Wqs) + (size_t)h*8192;
        unsigned short* D = (isK ? WkT : WqT) + (size_t)h*8192;
#pragma unroll
        for (int p = 0; p < 32; ++p) {
            int idx = p*256 + tid;                  // d*32 + kk
            smem[(idx>>5)*33 + (idx&31)] = S[idx];
        }
        __syncthreads();
#pragma unroll
        for (int p = 0; p < 8; ++p) {
            int o4 = p*256 + tid;                   // kk*256 + d (ushort4 granule)
            int kk = o4 >> 6, d = (o4 & 63)*4;
            ushort4 o;
            o.x = f2bf(smem[(d+0)*33 + kk]); o.y = f2bf(smem[(d+1)*33 + kk]);
            o.z = f2bf(smem[(d+2)*33 + kk]); o.w = f2bf(smem[(d+3)*33 + kk]);
            *(ushort4*)(D + (size_t)kk*256 + d) = o;
        }
        return;
    }
    // 256x256 per-head transposes
    int r3 = bid - 528;
    const float* S; unsigned short* dst; int rs, hs;
    if (r3 < 128) { S = Wvs; dst = WvT; rs = 256;  hs = 65536; }
    else          { r3 -= 128; S = Wo; dst = WoT; rs = 2048; hs = 256; }
    int e0 = (r3 & 3)*64, d0 = ((r3>>2) & 3)*64, h = r3 >> 4;
    float (*T)[69] = (float(*)[69])smem;
    const float* Sh = S + (size_t)h*65536;
    int ty = tid>>4, c4 = tid&15;
#pragma unroll
    for (int p = 0; p < 4; ++p) {
        int r = p*16 + ty;
        float4 v = *(const float4*)(Sh + (size_t)(d0+r)*256 + e0 + c4*4);
        T[r][c4*4+0]=v.x; T[r][c4*4+1]=v.y; T[r][c4*4+2]=v.z; T[r][c4*4+3]=v.w;
    }
    __syncthreads();
    unsigned short* D = dst + (size_t)h*hs;
#pragma unroll
    for (int p = 0; p < 4; ++p) {
        int er = p*16 + ty;
        ushort4 o;
        o.x = f2bf(T[c4*4+0][er]); o.y = f2bf(T[c4*4+1][er]);
        o.z = f2bf(T[c4*4+2][er]); o.w = f2bf(T[c4*4+3][er]);
        *(ushort4*)(D + (size_t)(e0+er)*rs + d0 + c4*4) = o;
    }
}

// ---------------- kernel 2: all projections via MFMA -------------------------
// grid (4, 32, 10): z<8 -> V head z (e0=x*64, m0=y*64); z==8 -> Q; z==9 -> K.
__global__ __launch_bounds__(256) void k_proj(
    const unsigned short* __restrict__ xb, const unsigned short* __restrict__ WqT,
    const unsigned short* __restrict__ WkT, const unsigned short* __restrict__ WvT,
    unsigned short* __restrict__ Qb, unsigned short* __restrict__ Kb,
    unsigned short* __restrict__ Vt)
{
    int z = blockIdx.z;
    int m0 = blockIdx.y*64, n0 = blockIdx.x*64;
    int tid = threadIdx.x, w = tid>>6, l15 = tid&15, g = (tid>>4)&3;
    f32x4 zf = {0.f,0.f,0.f,0.f};
    f32x4 acc[4] = {zf,zf,zf,zf};
    const unsigned short* arow = xb + (size_t)(m0+16*w+l15)*256 + 8*g;
    const unsigned short* W;
    if (z < 8)       W = WvT + (size_t)z*65536;
    else if (z == 8) W = WqT;
    else             W = WkT;
#pragma unroll
    for (int kk = 0; kk < 8; ++kk) {
        bf16x8 af = *(const bf16x8*)(arow + kk*32);
#pragma unroll
        for (int nt = 0; nt < 4; ++nt) {
            bf16x8 bf = *(const bf16x8*)(W + (size_t)(n0+16*nt+l15)*256 + kk*32 + 8*g);
            acc[nt] = __builtin_amdgcn_mfma_f32_16x16x32_bf16(af, bf, acc[nt], 0, 0, 0);
        }
    }
    if (z < 8) {                       // Vt[h*32+bsTile][e][t]
        unsigned short* VtT = Vt + ((size_t)z*32 + blockIdx.y)*(256*64);
#pragma unroll
        for (int nt = 0; nt < 4; ++nt) {
            ushort4 o = {f2bf(acc[nt][0]), f2bf(acc[nt][1]), f2bf(acc[nt][2]), f2bf(acc[nt][3])};
            *(ushort4*)(VtT + (size_t)(n0+16*nt+l15)*64 + 16*w + 4*g) = o;
        }
    } else {
        unsigned short* dst = (z == 8) ? Qb : Kb;
        int bs_base = m0 + 16*w + 4*g;
#pragma unroll
        for (int nt = 0; nt < 4; ++nt) {
            int col = n0 + 16*nt + l15;             // h*32 + kk
            int h = col>>5, kk = col&31;
#pragma unroll
            for (int j = 0; j < 4; ++j) {
                int bs = bs_base + j;
                int b = bs>>10, s = bs&1023;
                float zv = acc[nt][j];
                zv = zv > 0.f ? zv + 1.f : expf(zv);
                dst[((size_t)(h*PB+b)*PS + s)*PK + kk] = f2bf(zv);
            }
        }
    }
}

// ---------------- kernel 3: cumsum(K') + den in one pass (bf16 in) -----------
__global__ void k_cumden(const unsigned short* __restrict__ Qb,
                         const unsigned short* __restrict__ Kb,
                         float* __restrict__ den) {
    int hb  = blockIdx.x;
    int tid = threadIdx.x;
    int c = tid >> 5, kk = tid & 31;
    size_t base = (size_t)hb*(PS*PK) + (size_t)c*128*PK + kk;
    float sum = 0.f;
#pragma unroll 8
    for (int i = 0; i < 128; ++i) sum += bf2f(Kb[base + i*PK]);
    __shared__ float ssum[8][32];
    ssum[c][kk] = sum;
    __syncthreads();
    float acc = 0.f;
    for (int j = 0; j < c; ++j) acc += ssum[j][kk];
#pragma unroll 4
    for (int i = 0; i < 128; ++i) {
        acc += bf2f(Kb[base + i*PK]);
        float t = bf2f(Qb[base + i*PK]) * acc;
        t += __shfl_xor(t, 1);  t += __shfl_xor(t, 2);
        t += __shfl_xor(t, 4);  t += __shfl_xor(t, 8);
        t += __shfl_xor(t, 16);
        if (kk == 0) den[hb*PS + c*128 + i] = t + EPS;
    }
}

// ---------------- kernel 4: att strip = zeros + strictly-lower tiles ---------
// grid (st 16, hb 16) = 256 uniform blocks; each owns 64 att rows.
__global__ __launch_bounds__(256) void k_att(
    const unsigned short* __restrict__ Qb, const unsigned short* __restrict__ Kb,
    const float* __restrict__ den, float* __restrict__ att)
{
    int st = blockIdx.x, hb = blockIdx.y;
    int s0 = st*64;
    int tid = threadIdx.x, w = tid>>6, l15 = tid&15, g = (tid>>4)&3;

    alignas(16) __shared__ float PT[64][68];
    __shared__ float rden[64];

    float* attb = att + (size_t)hb*PS*PS;
    // ---- zero rectangle: rows [s0,s0+64), cols [s0+64, 1024) ----
    int c0 = s0 + 64;
    int nzf4 = (PS - c0) >> 2;
    if (nzf4 > 0 && tid < nzf4) {
        float4 z = {0.f,0.f,0.f,0.f};
        float* zb = attb + (size_t)s0*PS + c0 + tid*4;
#pragma unroll 4
        for (int r = 0; r < 64; ++r)
            *(float4*)(zb + (size_t)r*PS) = z;
    }
    if (tid < 64) rden[tid] = 1.0f / den[hb*PS + s0 + tid];

    if (st == 0) return;                   // no lower tiles

    bf16x8 qf = *(const bf16x8*)(Qb + ((size_t)hb*PS + s0 + 16*w + l15)*PK + 8*g);
    f32x4 zf = {0.f,0.f,0.f,0.f};
    __syncthreads();                       // rden ready
    float rd[4];
#pragma unroll
    for (int j = 0; j < 4; ++j) rd[j] = rden[16*w + 4*g + j];

    for (int tt = 0; tt < st; ++tt) {
        int t0 = tt*64;
        f32x4 p[4];
#pragma unroll
        for (int nt = 0; nt < 4; ++nt) {
            bf16x8 kf = *(const bf16x8*)(Kb + ((size_t)hb*PS + t0 + 16*nt + l15)*PK + 8*g);
            p[nt] = __builtin_amdgcn_mfma_f32_16x16x32_bf16(qf, kf, zf, 0, 0, 0);
        }
#pragma unroll
        for (int nt = 0; nt < 4; ++nt)
#pragma unroll
            for (int j = 0; j < 4; ++j)
                PT[16*w + 4*g + j][16*nt + l15] = p[nt][j] * rd[j];
        __syncthreads();                   // PT ready
#pragma unroll
        for (int pp = 0; pp < 4; ++pp) {
            int f4 = tid + pp*256;         // 0..1023: r = f4>>4, c4 = f4&15
            int r = f4 >> 4, c4 = f4 & 15;
            float4 v = *(const float4*)&PT[r][c4*4];
            *(float4*)(attb + (size_t)(s0+r)*PS + t0 + c4*4) = v;
        }
        __syncthreads();                   // PT reusable
    }
}

// ---------------- kernel 5: per-chunk KV sums --------------------------------
// KVs[hb*16+c][e 256][k 32] f32 = sum_{t in chunk c} Vt[e][t] * K'[t][k]
__global__ __launch_bounds__(256) void k_kv_sums(
    const unsigned short* __restrict__ Kb, const unsigned short* __restrict__ Vt,
    float* __restrict__ KVs)
{
    int c = blockIdx.x, hb = blockIdx.y;
    int tid = threadIdx.x, w = tid>>6, l15 = tid&15, g = (tid>>4)&3;
    __shared__ unsigned short KT[32*72];        // K'^T [kk][t]
#pragma unroll
    for (int i = 0; i < 8; ++i) {
        int flat = tid + i*256;                 // t = flat>>5, k = flat&31
        KT[(flat&31)*72 + (flat>>5)] = Kb[((size_t)hb*PS + c*64 + (flat>>5))*PK + (flat&31)];
    }
    __syncthreads();
    const unsigned short* Vtt = Vt + ((size_t)hb*16 + c)*(256*64);
    f32x4 zf = {0.f,0.f,0.f,0.f};
    f32x4 acc[4][2];
#pragma unroll
    for (int mt = 0; mt < 4; ++mt) { acc[mt][0] = zf; acc[mt][1] = zf; }
#pragma unroll
    for (int ks = 0; ks < 2; ++ks) {
        bf16x8 af[4];
#pragma unroll
        for (int mt = 0; mt < 4; ++mt)
            af[mt] = *(const bf16x8*)(Vtt + (size_t)(64*w + 16*mt + l15)*64 + 32*ks + 8*g);
#pragma unroll
        for (int nt = 0; nt < 2; ++nt) {
            bf16x8 bf = *(const bf16x8*)(KT + (16*nt + l15)*72 + 32*ks + 8*g);
#pragma unroll
            for (int mt = 0; mt < 4; ++mt)
                acc[mt][nt] = __builtin_amdgcn_mfma_f32_16x16x32_bf16(af[mt], bf, acc[mt][nt], 0, 0, 0);
        }
    }
    float* o = KVs + ((size_t)hb*16 + c)*8192;
#pragma unroll
    for (int mt = 0; mt < 4; ++mt)
#pragma unroll
        for (int nt = 0; nt < 2; ++nt)
#pragma unroll
            for (int j = 0; j < 4; ++j)
                o[(size_t)(64*w + 16*mt + 4*g + j)*32 + 16*nt + l15] = acc[mt][nt][j];
}

// ---------------- kernel 6: exclusive scan of KV over chunks -> bf16 ---------
__global__ void k_kv_scan(const float* __restrict__ KVs, unsigned short* __restrict__ KVpre) {
    int hb = blockIdx.y;
    int i = blockIdx.x*256 + threadIdx.x;       // 0..8191 = e*32+k
    const float* src = KVs + (size_t)hb*16*8192 + i;
    unsigned short* dst = KVpre + (size_t)hb*16*8192 + i;
    float acc = 0.f;
#pragma unroll
    for (int c = 0; c < 16; ++c) { dst[c*8192] = f2bf(acc); acc += src[c*8192]; }
}

// ---------------- kernel 7: node = rden*(q.KVpre) + att_diag@V ---------------
// also writes the diagonal att tiles. grid (chunk 16, hb 16).
__global__ __launch_bounds__(256) void k_node(
    const unsigned short* __restrict__ Qb, const unsigned short* __restrict__ Kb,
    const float* __restrict__ den, const unsigned short* __restrict__ Vt,
    const unsigned short* __restrict__ KVpre,
    float* __restrict__ att, unsigned short* __restrict__ nodeB)
{
    int c = blockIdx.x, hb = blockIdx.y;
    int s0 = c*64;
    int tid = threadIdx.x, w = tid>>6, l15 = tid&15, g = (tid>>4)&3;
    __shared__ unsigned short PL[64*72];
    __shared__ float rden[64];
    if (tid < 64) rden[tid] = 1.0f / den[hb*PS + s0 + tid];

    f32x4 zf = {0.f,0.f,0.f,0.f};
    bf16x8 qf = *(const bf16x8*)(Qb + ((size_t)hb*PS + s0 + 16*w + l15)*PK + 8*g);

    // prior: acc[nt] = q . KVpre  (e-tile nt)
    const unsigned short* KVp = KVpre + ((size_t)hb*16 + c)*8192;
    f32x4 acc[16];
#pragma unroll
    for (int nt = 0; nt < 16; ++nt) {
        bf16x8 bf = *(const bf16x8*)(KVp + (size_t)(16*nt + l15)*32 + 8*g);
        acc[nt] = __builtin_amdgcn_mfma_f32_16x16x32_bf16(qf, bf, zf, 0, 0, 0);
    }
    // diagonal P tile
    f32x4 p[4];
#pragma unroll
    for (int nt4 = 0; nt4 < 4; ++nt4) {
        bf16x8 kf = *(const bf16x8*)(Kb + ((size_t)hb*PS + s0 + 16*nt4 + l15)*PK + 8*g);
        p[nt4] = __builtin_amdgcn_mfma_f32_16x16x32_bf16(qf, kf, zf, 0, 0, 0);
    }
    __syncthreads();                            // rden ready
    float* attb = att + (size_t)hb*PS*PS;
#pragma unroll
    for (int nt4 = 0; nt4 < 4; ++nt4) {
#pragma unroll
        for (int j = 0; j < 4; ++j) {
            int r = 16*w + 4*g + j;
            int tc = 16*nt4 + l15;
            float v = p[nt4][j] * rden[r];
            if (tc > r) v = 0.f;
            attb[(size_t)(s0 + r)*PS + s0 + tc] = v;
            PL[r*72 + tc] = f2bf(v);
        }
    }
    // scale prior by rden
#pragma unroll
    for (int nt = 0; nt < 16; ++nt)
#pragma unroll
        for (int j = 0; j < 4; ++j)
            acc[nt][j] *= rden[16*w + 4*g + j];
    __syncthreads();                            // PL ready
    // PV: wave w = m-strip w (rows 16w..16w+15), A = PL, B = Vt[e][t]
    const unsigned short* Vtt = Vt + ((size_t)hb*16 + c)*(256*64);
#pragma unroll
    for (int ks = 0; ks < 2; ++ks) {
        bf16x8 af = *(const bf16x8*)(PL + (size_t)(16*w + l15)*72 + 32*ks + 8*g);
#pragma unroll
        for (int nt = 0; nt < 16; ++nt) {
            bf16x8 vf = *(const bf16x8*)(Vtt + (size_t)(16*nt + l15)*64 + 32*ks + 8*g);
            acc[nt] = __builtin_amdgcn_mfma_f32_16x16x32_bf16(af, vf, acc[nt], 0, 0, 0);
        }
    }
    // store nodeB bf16 [bs][h*256+e]
    int h = hb >> 1, b = hb & 1;
    unsigned short* np = nodeB + ((size_t)(b*PS + s0))*2048 + h*256;
#pragma unroll
    for (int nt = 0; nt < 16; ++nt)
#pragma unroll
        for (int j = 0; j < 4; ++j)
            np[(size_t)(16*w + 4*g + j)*2048 + 16*nt + l15] = f2bf(acc[nt][j]);
}

// ---------------- kernel 8: out = nodeB @ WoT (full K, direct store) --------
__global__ __launch_bounds__(256) void k_out2(
    const unsigned short* __restrict__ nodeB, const unsigned short* __restrict__ WoT,
    float* __restrict__ out)
{
    int e0 = blockIdx.x*64, m0 = blockIdx.y*16;
    int tid = threadIdx.x, w = tid>>6, l15 = tid&15, g = (tid>>4)&3;
    f32x4 zf = {0.f,0.f,0.f,0.f};
    f32x4 acc = zf;
    const unsigned short* arow = nodeB + (size_t)(m0 + l15)*2048 + 8*g;
    const unsigned short* brow = WoT + (size_t)(e0 + 16*w + l15)*2048 + 8*g;
#pragma unroll 8
    for (int kk = 0; kk < 64; ++kk) {
        bf16x8 af = *(const bf16x8*)(arow + kk*32);
        bf16x8 bf = *(const bf16x8*)(brow + kk*32);
        acc = __builtin_amdgcn_mfma_f32_16x16x32_bf16(af, bf, acc, 0, 0, 0);
    }
#pragma unroll
    for (int j = 0; j < 4; ++j)
        out[(size_t)(m0 + 4*g + j)*PD + e0 + 16*w + l15] = acc[j];
}

// ---------------- launch ------------------------------------------------------
extern "C" void kernel_launch(void* const* d_in, const int* in_sizes, int n_in,
                              void* d_out, int out_size, void* d_ws, size_t ws_size,
                              hipStream_t stream) {
    const float* x   = (const float*)d_in[0];
    const float* Wks = (const float*)d_in[1];
    const float* Wqs = (const float*)d_in[2];
    const float* Wvs = (const float*)d_in[3];
    const float* Wo  = (const float*)d_in[4];

    float* out = (float*)d_out;                     // [B,S,D]
    float* att = (float*)d_out + (size_t)PB*PS*PD;  // [H,B,S,S]

    // workspace layout (float offsets)
    float* ws = (float*)d_ws;
    float*          den   = ws + 0;                            //    16,384 f
    unsigned short* Qb    = (unsigned short*)(ws + 16384);     //   524,288 u16
    unsigned short* Kb    = (unsigned short*)(ws + 278528);    //   524,288 u16
    unsigned short* Vt    = (unsigned short*)(ws + 540672);    // 4,194,304 u16
    unsigned short* xb    = (unsigned short*)(ws + 2637824);   //   524,288 u16
    unsigned short* WqT   = (unsigned short*)(ws + 2899968);   //    65,536 u16
    unsigned short* WkT   = (unsigned short*)(ws + 2932736);   //    65,536 u16
    unsigned short* WvT   = (unsigned short*)(ws + 2965504);   //   524,288 u16
    unsigned short* WoT   = (unsigned short*)(ws + 3227648);   //   524,288 u16
    unsigned short* nodeB = (unsigned short*)(ws + 3489792);   // 4,194,304 u16
    float*          KVs   = ws + 5586944;                      // 2,097,152 f
    unsigned short* KVpre = (unsigned short*)(ws + 7684096);   // 2,097,152 u16
    const size_t needed = (size_t)8732672 * 4;
    if (ws_size < needed) {
        fprintf(stderr, "kernel_launch: ws_size %zu < needed %zu\n", ws_size, needed);
        return;
    }

    k_prep<<<784, 256, 0, stream>>>(x, Wqs, Wks, Wvs, Wo, xb, WqT, WkT, WvT, WoT);
    k_proj<<<dim3(4, 32, 10), 256, 0, stream>>>(xb, WqT, WkT, WvT, Qb, Kb, Vt);
    k_cumden<<<HB, 256, 0, stream>>>(Qb, Kb, den);
    k_att<<<dim3(16, HB), 256, 0, stream>>>(Qb, Kb, den, att);
    k_kv_sums<<<dim3(16, HB), 256, 0, stream>>>(Kb, Vt, KVs);
    k_kv_scan<<<dim3(32, HB), 256, 0, stream>>>(KVs, KVpre);
    k_node<<<dim3(16, HB), 256, 0, stream>>>(Qb, Kb, den, Vt, KVpre, att, nodeB);
    k_out2<<<dim3(4, 128), 256, 0, stream>>>(nodeB, WoT, out);
}

// Round 7
// 102.891 us; speedup vs baseline: 1.4974x; 1.4974x over previous
//
#include <hip/hip_runtime.h>
#include <hip/hip_bf16.h>
#include <cstdio>

// Problem constants: B=2, S=1024, D=256, H=8, K=32
#define PB 2
#define PS 1024
#define PD 256
#define PK 32
#define PH 8
#define HB (PH*PB)          // 16
#define BS (PB*PS)          // 2048
#define EPS 1e-9f

typedef __attribute__((ext_vector_type(8))) short bf16x8;
typedef __attribute__((ext_vector_type(4))) float f32x4;

__device__ inline unsigned short f2bf(float f) {
    __hip_bfloat16 h = __float2bfloat16(f);
    return *reinterpret_cast<unsigned short*>(&h);
}
__device__ inline float bf2f(unsigned short u) {
    return __bfloat162float(*reinterpret_cast<__hip_bfloat16*>(&u));
}

// ---------------- kernel 1: fused prep (xb, WqT, WkT, WvT, WoT) --------------
// flat grid 784: [0,512) xb; [512,528) qk-transpose; [528,656) WvT; [656,784) WoT
__global__ __launch_bounds__(256) void k_prep(
    const float* __restrict__ x, const float* __restrict__ Wqs,
    const float* __restrict__ Wks, const float* __restrict__ Wvs,
    const float* __restrict__ Wo,
    unsigned short* __restrict__ xb, unsigned short* __restrict__ WqT,
    unsigned short* __restrict__ WkT, unsigned short* __restrict__ WvT,
    unsigned short* __restrict__ WoT)
{
    __shared__ float smem[8448];
    int bid = blockIdx.x, tid = threadIdx.x;
    if (bid < 512) {                       // xb: f32 -> bf16
        int i = bid*256 + tid;
        float4 v = ((const float4*)x)[i];
        ushort4 o = {f2bf(v.x), f2bf(v.y), f2bf(v.z), f2bf(v.w)};
        ((ushort4*)xb)[i] = o;
        return;
    }
    if (bid < 528) {                       // Wq/Wk [d 256][kk 32] -> [kk][d]
        int r2 = bid - 512;
        int h = r2 >> 1, isK = r2 & 1;
        const float* S = (isK ? Wks : Wqs) + (size_t)h*8192;
        unsigned short* D = (isK ? WkT : WqT) + (size_t)h*8192;
#pragma unroll
        for (int p = 0; p < 32; ++p) {
            int idx = p*256 + tid;                  // d*32 + kk
            smem[(idx>>5)*33 + (idx&31)] = S[idx];
        }
        __syncthreads();
#pragma unroll
        for (int p = 0; p < 8; ++p) {
            int o4 = p*256 + tid;                   // kk*256 + d (ushort4 granule)
            int kk = o4 >> 6, d = (o4 & 63)*4;
            ushort4 o;
            o.x = f2bf(smem[(d+0)*33 + kk]); o.y = f2bf(smem[(d+1)*33 + kk]);
            o.z = f2bf(smem[(d+2)*33 + kk]); o.w = f2bf(smem[(d+3)*33 + kk]);
            *(ushort4*)(D + (size_t)kk*256 + d) = o;
        }
        return;
    }
    // 256x256 per-head transposes
    int r3 = bid - 528;
    const float* S; unsigned short* dst; int rs, hs;
    if (r3 < 128) { S = Wvs; dst = WvT; rs = 256;  hs = 65536; }
    else          { r3 -= 128; S = Wo; dst = WoT; rs = 2048; hs = 256; }
    int e0 = (r3 & 3)*64, d0 = ((r3>>2) & 3)*64, h = r3 >> 4;
    float (*T)[69] = (float(*)[69])smem;
    const float* Sh = S + (size_t)h*65536;
    int ty = tid>>4, c4 = tid&15;
#pragma unroll
    for (int p = 0; p < 4; ++p) {
        int r = p*16 + ty;
        float4 v = *(const float4*)(Sh + (size_t)(d0+r)*256 + e0 + c4*4);
        T[r][c4*4+0]=v.x; T[r][c4*4+1]=v.y; T[r][c4*4+2]=v.z; T[r][c4*4+3]=v.w;
    }
    __syncthreads();
    unsigned short* D = dst + (size_t)h*hs;
#pragma unroll
    for (int p = 0; p < 4; ++p) {
        int er = p*16 + ty;
        ushort4 o;
        o.x = f2bf(T[c4*4+0][er]); o.y = f2bf(T[c4*4+1][er]);
        o.z = f2bf(T[c4*4+2][er]); o.w = f2bf(T[c4*4+3][er]);
        *(ushort4*)(D + (size_t)(e0+er)*rs + d0 + c4*4) = o;
    }
}

// ---------------- kernel 2: all projections via MFMA -------------------------
// grid (4, 32, 10): z<8 -> V head z; z==8 -> Q; z==9 -> K.
__global__ __launch_bounds__(256) void k_proj(
    const unsigned short* __restrict__ xb, const unsigned short* __restrict__ WqT,
    const unsigned short* __restrict__ WkT, const unsigned short* __restrict__ WvT,
    unsigned short* __restrict__ Qb, unsigned short* __restrict__ Kb,
    unsigned short* __restrict__ Vt)
{
    int z = blockIdx.z;
    int m0 = blockIdx.y*64, n0 = blockIdx.x*64;
    int tid = threadIdx.x, w = tid>>6, l15 = tid&15, g = (tid>>4)&3;
    f32x4 zf = {0.f,0.f,0.f,0.f};
    f32x4 acc[4] = {zf,zf,zf,zf};
    const unsigned short* arow = xb + (size_t)(m0+16*w+l15)*256 + 8*g;
    const unsigned short* W;
    if (z < 8)       W = WvT + (size_t)z*65536;
    else if (z == 8) W = WqT;
    else             W = WkT;
#pragma unroll
    for (int kk = 0; kk < 8; ++kk) {
        bf16x8 af = *(const bf16x8*)(arow + kk*32);
#pragma unroll
        for (int nt = 0; nt < 4; ++nt) {
            bf16x8 bf = *(const bf16x8*)(W + (size_t)(n0+16*nt+l15)*256 + kk*32 + 8*g);
            acc[nt] = __builtin_amdgcn_mfma_f32_16x16x32_bf16(af, bf, acc[nt], 0, 0, 0);
        }
    }
    if (z < 8) {                       // Vt[h*32+bsTile][e][t]
        unsigned short* VtT = Vt + ((size_t)z*32 + blockIdx.y)*(256*64);
#pragma unroll
        for (int nt = 0; nt < 4; ++nt) {
            ushort4 o = {f2bf(acc[nt][0]), f2bf(acc[nt][1]), f2bf(acc[nt][2]), f2bf(acc[nt][3])};
            *(ushort4*)(VtT + (size_t)(n0+16*nt+l15)*64 + 16*w + 4*g) = o;
        }
    } else {
        unsigned short* dst = (z == 8) ? Qb : Kb;
        int bs_base = m0 + 16*w + 4*g;
#pragma unroll
        for (int nt = 0; nt < 4; ++nt) {
            int col = n0 + 16*nt + l15;             // h*32 + kk
            int h = col>>5, kk = col&31;
#pragma unroll
            for (int j = 0; j < 4; ++j) {
                int bs = bs_base + j;
                int b = bs>>10, s = bs&1023;
                float zv = acc[nt][j];
                zv = zv > 0.f ? zv + 1.f : expf(zv);
                dst[((size_t)(h*PB+b)*PS + s)*PK + kk] = f2bf(zv);
            }
        }
    }
}

// ---------------- kernel 3: per-chunk KV sums + per-chunk K sums -------------
// KVs[hb*16+c][e 256][k 32] f32 = sum_{t in chunk c} Vt[e][t] * K'[t][k]
// Ksum[hb*16+c][k 32] f32     = sum_{t in chunk c} K'[t][k]
__global__ __launch_bounds__(256) void k_kv_sums(
    const unsigned short* __restrict__ Kb, const unsigned short* __restrict__ Vt,
    float* __restrict__ KVs, float* __restrict__ Ksum)
{
    int c = blockIdx.x, hb = blockIdx.y;
    int tid = threadIdx.x, w = tid>>6, l15 = tid&15, g = (tid>>4)&3;
    __shared__ unsigned short KT[32*72];        // K'^T [kk][t]
    __shared__ float partial[8][32];
#pragma unroll
    for (int i = 0; i < 8; ++i) {
        int flat = tid + i*256;                 // t = flat>>5, k = flat&31
        KT[(flat&31)*72 + (flat>>5)] = Kb[((size_t)hb*PS + c*64 + (flat>>5))*PK + (flat&31)];
    }
    __syncthreads();
    // --- K chunk sums (f32) ---
    {
        int kk = tid & 31, part = tid >> 5;     // 8 parts x 8 t each
        float s = 0.f;
#pragma unroll
        for (int i = 0; i < 8; ++i) s += bf2f(KT[kk*72 + part*8 + i]);
        partial[part][kk] = s;
    }
    // --- KV sums via MFMA ---
    const unsigned short* Vtt = Vt + ((size_t)hb*16 + c)*(256*64);
    f32x4 zf = {0.f,0.f,0.f,0.f};
    f32x4 acc[4][2];
#pragma unroll
    for (int mt = 0; mt < 4; ++mt) { acc[mt][0] = zf; acc[mt][1] = zf; }
#pragma unroll
    for (int ks = 0; ks < 2; ++ks) {
        bf16x8 af[4];
#pragma unroll
        for (int mt = 0; mt < 4; ++mt)
            af[mt] = *(const bf16x8*)(Vtt + (size_t)(64*w + 16*mt + l15)*64 + 32*ks + 8*g);
#pragma unroll
        for (int nt = 0; nt < 2; ++nt) {
            bf16x8 bf = *(const bf16x8*)(KT + (16*nt + l15)*72 + 32*ks + 8*g);
#pragma unroll
            for (int mt = 0; mt < 4; ++mt)
                acc[mt][nt] = __builtin_amdgcn_mfma_f32_16x16x32_bf16(af[mt], bf, acc[mt][nt], 0, 0, 0);
        }
    }
    __syncthreads();
    if (tid < 32) {
        float s = 0.f;
#pragma unroll
        for (int p = 0; p < 8; ++p) s += partial[p][tid];
        Ksum[((size_t)hb*16 + c)*32 + tid] = s;
    }
    float* o = KVs + ((size_t)hb*16 + c)*8192;
#pragma unroll
    for (int mt = 0; mt < 4; ++mt)
#pragma unroll
        for (int nt = 0; nt < 2; ++nt)
#pragma unroll
            for (int j = 0; j < 4; ++j)
                o[(size_t)(64*w + 16*mt + 4*g + j)*32 + 16*nt + l15] = acc[mt][nt][j];
}

// ---------------- kernel 4: exclusive scans over chunks ----------------------
// blockIdx.x < 32: KV scan -> KVpre bf16; blockIdx.x == 32: Ksum scan -> Kpre f32
__global__ void k_kv_scan(const float* __restrict__ KVs, const float* __restrict__ Ksum,
                          unsigned short* __restrict__ KVpre, float* __restrict__ Kpre) {
    int hb = blockIdx.y;
    if (blockIdx.x == 32) {
        int kk = threadIdx.x;
        if (kk < 32) {
            float acc = 0.f;
#pragma unroll
            for (int c = 0; c < 16; ++c) {
                Kpre[((size_t)hb*16 + c)*32 + kk] = acc;
                acc += Ksum[((size_t)hb*16 + c)*32 + kk];
            }
        }
        return;
    }
    int i = blockIdx.x*256 + threadIdx.x;       // 0..8191 = e*32+k
    const float* src = KVs + (size_t)hb*16*8192 + i;
    unsigned short* dst = KVpre + (size_t)hb*16*8192 + i;
    float acc = 0.f;
#pragma unroll
    for (int c = 0; c < 16; ++c) { dst[c*8192] = f2bf(acc); acc += src[c*8192]; }
}

// ---------------- kernel 5: den via LDS scan (grid 16 c x 16 hb) -------------
// den[s] = q[s] . (Kpre[c] + inclusive-cumsum_{chunk}(K)[s]) + EPS
__global__ __launch_bounds__(256) void k_den2(
    const unsigned short* __restrict__ Qb, const unsigned short* __restrict__ Kb,
    const float* __restrict__ Kpre, float* __restrict__ den)
{
    int c = blockIdx.x, hb = blockIdx.y;
    int tid = threadIdx.x;
    int r = tid >> 2, quad = tid & 3;           // row 0..63, 8 kk per quad
    __shared__ float kc[64][33];
    bf16x8 k8 = *(const bf16x8*)(Kb + ((size_t)hb*PS + c*64 + r)*PK + quad*8);
#pragma unroll
    for (int i = 0; i < 8; ++i) kc[r][quad*8+i] = bf2f((unsigned short)k8[i]);
    __syncthreads();
    // Hillis-Steele inclusive scan over rows
#pragma unroll
    for (int st = 1; st < 64; st <<= 1) {
        float tmp[8];
#pragma unroll
        for (int i = 0; i < 8; ++i) tmp[i] = (r >= st) ? kc[r-st][quad*8+i] : 0.f;
        __syncthreads();
#pragma unroll
        for (int i = 0; i < 8; ++i) kc[r][quad*8+i] += tmp[i];
        __syncthreads();
    }
    bf16x8 q8 = *(const bf16x8*)(Qb + ((size_t)hb*PS + c*64 + r)*PK + quad*8);
    const float* Kp = Kpre + ((size_t)hb*16 + c)*32 + quad*8;
    float p = 0.f;
#pragma unroll
    for (int i = 0; i < 8; ++i)
        p += bf2f((unsigned short)q8[i]) * (Kp[i] + kc[r][quad*8+i]);
    p += __shfl_xor(p, 1);
    p += __shfl_xor(p, 2);
    if (quad == 0) den[hb*PS + c*64 + r] = p + EPS;
}

// ---------------- kernel 6: att strip = zeros + strictly-lower tiles ---------
__global__ __launch_bounds__(256) void k_att(
    const unsigned short* __restrict__ Qb, const unsigned short* __restrict__ Kb,
    const float* __restrict__ den, float* __restrict__ att)
{
    int st = blockIdx.x, hb = blockIdx.y;
    int s0 = st*64;
    int tid = threadIdx.x, w = tid>>6, l15 = tid&15, g = (tid>>4)&3;

    alignas(16) __shared__ float PT[64][68];
    __shared__ float rden[64];

    float* attb = att + (size_t)hb*PS*PS;
    // ---- zero rectangle: rows [s0,s0+64), cols [s0+64, 1024) ----
    int c0 = s0 + 64;
    int nzf4 = (PS - c0) >> 2;
    if (nzf4 > 0 && tid < nzf4) {
        float4 z = {0.f,0.f,0.f,0.f};
        float* zb = attb + (size_t)s0*PS + c0 + tid*4;
#pragma unroll 4
        for (int r = 0; r < 64; ++r)
            *(float4*)(zb + (size_t)r*PS) = z;
    }
    if (tid < 64) rden[tid] = 1.0f / den[hb*PS + s0 + tid];

    if (st == 0) return;                   // no lower tiles

    bf16x8 qf = *(const bf16x8*)(Qb + ((size_t)hb*PS + s0 + 16*w + l15)*PK + 8*g);
    f32x4 zf = {0.f,0.f,0.f,0.f};
    __syncthreads();                       // rden ready
    float rd[4];
#pragma unroll
    for (int j = 0; j < 4; ++j) rd[j] = rden[16*w + 4*g + j];

    for (int tt = 0; tt < st; ++tt) {
        int t0 = tt*64;
        f32x4 p[4];
#pragma unroll
        for (int nt = 0; nt < 4; ++nt) {
            bf16x8 kf = *(const bf16x8*)(Kb + ((size_t)hb*PS + t0 + 16*nt + l15)*PK + 8*g);
            p[nt] = __builtin_amdgcn_mfma_f32_16x16x32_bf16(qf, kf, zf, 0, 0, 0);
        }
#pragma unroll
        for (int nt = 0; nt < 4; ++nt)
#pragma unroll
            for (int j = 0; j < 4; ++j)
                PT[16*w + 4*g + j][16*nt + l15] = p[nt][j] * rd[j];
        __syncthreads();                   // PT ready
#pragma unroll
        for (int pp = 0; pp < 4; ++pp) {
            int f4 = tid + pp*256;         // r = f4>>4, c4 = f4&15
            int r = f4 >> 4, c4 = f4 & 15;
            float4 v = *(const float4*)&PT[r][c4*4];
            *(float4*)(attb + (size_t)(s0+r)*PS + t0 + c4*4) = v;
        }
        __syncthreads();                   // PT reusable
    }
}

// ---------------- kernel 7: node = rden*(q.KVpre) + att_diag@V ---------------
__global__ __launch_bounds__(256) void k_node(
    const unsigned short* __restrict__ Qb, const unsigned short* __restrict__ Kb,
    const float* __restrict__ den, const unsigned short* __restrict__ Vt,
    const unsigned short* __restrict__ KVpre,
    float* __restrict__ att, unsigned short* __restrict__ nodeB)
{
    int c = blockIdx.x, hb = blockIdx.y;
    int s0 = c*64;
    int tid = threadIdx.x, w = tid>>6, l15 = tid&15, g = (tid>>4)&3;
    __shared__ unsigned short PL[64*72];
    __shared__ float rden[64];
    if (tid < 64) rden[tid] = 1.0f / den[hb*PS + s0 + tid];

    f32x4 zf = {0.f,0.f,0.f,0.f};
    bf16x8 qf = *(const bf16x8*)(Qb + ((size_t)hb*PS + s0 + 16*w + l15)*PK + 8*g);

    const unsigned short* KVp = KVpre + ((size_t)hb*16 + c)*8192;
    f32x4 acc[16];
#pragma unroll
    for (int nt = 0; nt < 16; ++nt) {
        bf16x8 bf = *(const bf16x8*)(KVp + (size_t)(16*nt + l15)*32 + 8*g);
        acc[nt] = __builtin_amdgcn_mfma_f32_16x16x32_bf16(qf, bf, zf, 0, 0, 0);
    }
    f32x4 p[4];
#pragma unroll
    for (int nt4 = 0; nt4 < 4; ++nt4) {
        bf16x8 kf = *(const bf16x8*)(Kb + ((size_t)hb*PS + s0 + 16*nt4 + l15)*PK + 8*g);
        p[nt4] = __builtin_amdgcn_mfma_f32_16x16x32_bf16(qf, kf, zf, 0, 0, 0);
    }
    __syncthreads();                            // rden ready
    float* attb = att + (size_t)hb*PS*PS;
#pragma unroll
    for (int nt4 = 0; nt4 < 4; ++nt4) {
#pragma unroll
        for (int j = 0; j < 4; ++j) {
            int r = 16*w + 4*g + j;
            int tc = 16*nt4 + l15;
            float v = p[nt4][j] * rden[r];
            if (tc > r) v = 0.f;
            attb[(size_t)(s0 + r)*PS + s0 + tc] = v;
            PL[r*72 + tc] = f2bf(v);
        }
    }
#pragma unroll
    for (int nt = 0; nt < 16; ++nt)
#pragma unroll
        for (int j = 0; j < 4; ++j)
            acc[nt][j] *= rden[16*w + 4*g + j];
    __syncthreads();                            // PL ready
    const unsigned short* Vtt = Vt + ((size_t)hb*16 + c)*(256*64);
#pragma unroll
    for (int ks = 0; ks < 2; ++ks) {
        bf16x8 af = *(const bf16x8*)(PL + (size_t)(16*w + l15)*72 + 32*ks + 8*g);
#pragma unroll
        for (int nt = 0; nt < 16; ++nt) {
            bf16x8 vf = *(const bf16x8*)(Vtt + (size_t)(16*nt + l15)*64 + 32*ks + 8*g);
            acc[nt] = __builtin_amdgcn_mfma_f32_16x16x32_bf16(af, vf, acc[nt], 0, 0, 0);
        }
    }
    int h = hb >> 1, b = hb & 1;
    unsigned short* np = nodeB + ((size_t)(b*PS + s0))*2048 + h*256;
#pragma unroll
    for (int nt = 0; nt < 16; ++nt)
#pragma unroll
        for (int j = 0; j < 4; ++j)
            np[(size_t)(16*w + 4*g + j)*2048 + 16*nt + l15] = f2bf(acc[nt][j]);
}

// ---------------- kernel 8: out = nodeB @ WoT (full K, direct store) --------
__global__ __launch_bounds__(256) void k_out2(
    const unsigned short* __restrict__ nodeB, const unsigned short* __restrict__ WoT,
    float* __restrict__ out)
{
    int e0 = blockIdx.x*64, m0 = blockIdx.y*16;
    int tid = threadIdx.x, w = tid>>6, l15 = tid&15, g = (tid>>4)&3;
    f32x4 zf = {0.f,0.f,0.f,0.f};
    f32x4 acc = zf;
    const unsigned short* arow = nodeB + (size_t)(m0 + l15)*2048 + 8*g;
    const unsigned short* brow = WoT + (size_t)(e0 + 16*w + l15)*2048 + 8*g;
#pragma unroll 8
    for (int kk = 0; kk < 64; ++kk) {
        bf16x8 af = *(const bf16x8*)(arow + kk*32);
        bf16x8 bf = *(const bf16x8*)(brow + kk*32);
        acc = __builtin_amdgcn_mfma_f32_16x16x32_bf16(af, bf, acc, 0, 0, 0);
    }
#pragma unroll
    for (int j = 0; j < 4; ++j)
        out[(size_t)(m0 + 4*g + j)*PD + e0 + 16*w + l15] = acc[j];
}

// ---------------- launch ------------------------------------------------------
extern "C" void kernel_launch(void* const* d_in, const int* in_sizes, int n_in,
                              void* d_out, int out_size, void* d_ws, size_t ws_size,
                              hipStream_t stream) {
    const float* x   = (const float*)d_in[0];
    const float* Wks = (const float*)d_in[1];
    const float* Wqs = (const float*)d_in[2];
    const float* Wvs = (const float*)d_in[3];
    const float* Wo  = (const float*)d_in[4];

    float* out = (float*)d_out;                     // [B,S,D]
    float* att = (float*)d_out + (size_t)PB*PS*PD;  // [H,B,S,S]

    // workspace layout (float offsets)
    float* ws = (float*)d_ws;
    float*          den   = ws + 0;                            //    16,384 f
    unsigned short* Qb    = (unsigned short*)(ws + 16384);     //   524,288 u16
    unsigned short* Kb    = (unsigned short*)(ws + 278528);    //   524,288 u16
    unsigned short* Vt    = (unsigned short*)(ws + 540672);    // 4,194,304 u16
    unsigned short* xb    = (unsigned short*)(ws + 2637824);   //   524,288 u16
    unsigned short* WqT   = (unsigned short*)(ws + 2899968);   //    65,536 u16
    unsigned short* WkT   = (unsigned short*)(ws + 2932736);   //    65,536 u16
    unsigned short* WvT   = (unsigned short*)(ws + 2965504);   //   524,288 u16
    unsigned short* WoT   = (unsigned short*)(ws + 3227648);   //   524,288 u16
    unsigned short* nodeB = (unsigned short*)(ws + 3489792);   // 4,194,304 u16
    float*          KVs   = ws + 5586944;                      // 2,097,152 f
    unsigned short* KVpre = (unsigned short*)(ws + 7684096);   // 2,097,152 u16
    float*          KsumG = ws + 8732672;                      //     8,192 f
    float*          KpreG = ws + 8740864;                      //     8,192 f
    const size_t needed = (size_t)8749056 * 4;
    if (ws_size < needed) {
        fprintf(stderr, "kernel_launch: ws_size %zu < needed %zu\n", ws_size, needed);
        return;
    }

    k_prep<<<784, 256, 0, stream>>>(x, Wqs, Wks, Wvs, Wo, xb, WqT, WkT, WvT, WoT);
    k_proj<<<dim3(4, 32, 10), 256, 0, stream>>>(xb, WqT, WkT, WvT, Qb, Kb, Vt);
    k_kv_sums<<<dim3(16, HB), 256, 0, stream>>>(Kb, Vt, KVs, KsumG);
    k_kv_scan<<<dim3(33, HB), 256, 0, stream>>>(KVs, KsumG, KVpre, KpreG);
    k_den2<<<dim3(16, HB), 256, 0, stream>>>(Qb, Kb, KpreG, den);
    k_att<<<dim3(16, HB), 256, 0, stream>>>(Qb, Kb, den, att);
    k_node<<<dim3(16, HB), 256, 0, stream>>>(Qb, Kb, den, Vt, KVpre, att, nodeB);
    k_out2<<<dim3(4, 128), 256, 0, stream>>>(nodeB, WoT, out);
}